// Round 1
// baseline (660.284 us; speedup 1.0000x reference)
//
#include <hip/hip_runtime.h>
#include <math.h>

#define B 8
#define M 8192
#define N 512
#define R 256
#define EPSF 1e-16f

// ---------------------------------------------------------------------------
// K1: fused  distances -> relu -> softmax(u) -> column-sum(u)
// grid (M/64, B), block 256.
// Per block: 64 rows of x vs all 256 centers (gathered on the fly via inds).
// LDS layout [k][m] so compute reads are float4 (a) / conflict-free b32 (b).
// ---------------------------------------------------------------------------
__global__ __launch_bounds__(256) void ekm_dist_softmax(
    const float* __restrict__ x, const float* __restrict__ alpha_p,
    const int* __restrict__ inds, float* __restrict__ u_out,
    float* __restrict__ colsum)
{
    __shared__ float As[16][68];    // [k][m]   68: float4-aligned pad
    __shared__ float Bs[16][257];   // [k][r]
    __shared__ float x2s[64];
    __shared__ float v2s[256];
    __shared__ float colLDS[8][256];

    const int t    = threadIdx.x;
    const int b    = blockIdx.y;
    const int mt   = blockIdx.x * 64;
    const int lrow = t >> 2;        // 0..63: A-load row / B-load r base
    const int kq   = (t & 3) * 4;   // 0,4,8,12

    // center row indices this thread gathers (4 passes of 64)
    int cind[4];
#pragma unroll
    for (int p = 0; p < 4; ++p) cind[p] = inds[lrow + 64 * p];

    const float* xb = x + (size_t)b * M * N;

    float acc[8][8];
#pragma unroll
    for (int i = 0; i < 8; ++i)
#pragma unroll
        for (int j = 0; j < 8; ++j) acc[i][j] = 0.f;

    float x2part = 0.f;
    float v2part[4] = {0.f, 0.f, 0.f, 0.f};

    const int tr = t >> 5;   // 0..7  (rows mt + tr*8 .. +7)
    const int tc = t & 31;   // 0..31 (cols tc + 32*j)

    for (int k0 = 0; k0 < N; k0 += 16) {
        float4 av = *(const float4*)(xb + (size_t)(mt + lrow) * N + k0 + kq);
        float4 bv[4];
#pragma unroll
        for (int p = 0; p < 4; ++p)
            bv[p] = *(const float4*)(xb + (size_t)cind[p] * N + k0 + kq);

        __syncthreads();   // previous tile fully consumed
        As[kq + 0][lrow] = av.x; As[kq + 1][lrow] = av.y;
        As[kq + 2][lrow] = av.z; As[kq + 3][lrow] = av.w;
        x2part += av.x * av.x + av.y * av.y + av.z * av.z + av.w * av.w;
#pragma unroll
        for (int p = 0; p < 4; ++p) {
            int r = lrow + 64 * p;
            Bs[kq + 0][r] = bv[p].x; Bs[kq + 1][r] = bv[p].y;
            Bs[kq + 2][r] = bv[p].z; Bs[kq + 3][r] = bv[p].w;
            v2part[p] += bv[p].x * bv[p].x + bv[p].y * bv[p].y
                       + bv[p].z * bv[p].z + bv[p].w * bv[p].w;
        }
        __syncthreads();

#pragma unroll
        for (int k = 0; k < 16; ++k) {
            float a[8], bb[8];
            *(float4*)&a[0] = *(const float4*)&As[k][tr * 8];
            *(float4*)&a[4] = *(const float4*)&As[k][tr * 8 + 4];
#pragma unroll
            for (int j = 0; j < 8; ++j) bb[j] = Bs[k][tc + 32 * j];
#pragma unroll
            for (int i = 0; i < 8; ++i)
#pragma unroll
                for (int j = 0; j < 8; ++j) acc[i][j] += a[i] * bb[j];
        }
    }

    // reduce x2 / v2 partials across the 4 lanes sharing one load-row
    x2part += __shfl_xor(x2part, 1);
    x2part += __shfl_xor(x2part, 2);
    if ((t & 3) == 0) x2s[lrow] = x2part;
#pragma unroll
    for (int p = 0; p < 4; ++p) {
        float v = v2part[p];
        v += __shfl_xor(v, 1);
        v += __shfl_xor(v, 2);
        if ((t & 3) == 0) v2s[lrow + 64 * p] = v;
    }
    __syncthreads();

    const float inv_alpha = 1.0f / alpha_p[0];
    float v2c[8];
#pragma unroll
    for (int j = 0; j < 8; ++j) v2c[j] = v2s[tc + 32 * j];

    float colp[8] = {0.f, 0.f, 0.f, 0.f, 0.f, 0.f, 0.f, 0.f};
    float* ub = u_out + ((size_t)b * M + mt) * R;

#pragma unroll
    for (int i = 0; i < 8; ++i) {
        const int row = tr * 8 + i;
        const float x2v = x2s[row];
        float d[8];
        float dmin = 3.4e38f;
#pragma unroll
        for (int j = 0; j < 8; ++j) {
            float dd = x2v - 2.f * acc[i][j] + v2c[j];
            dd = fmaxf(dd, 0.f);                 // relu, matches ref
            d[j] = dd;
            dmin = fminf(dmin, dd);
        }
        // min over the 32 lanes holding this row
#pragma unroll
        for (int off = 1; off < 32; off <<= 1)
            dmin = fminf(dmin, __shfl_xor(dmin, off));
        float e[8];
        float s = 0.f;
#pragma unroll
        for (int j = 0; j < 8; ++j) {
            e[j] = expf((dmin - d[j]) * inv_alpha);
            s += e[j];
        }
#pragma unroll
        for (int off = 1; off < 32; off <<= 1) s += __shfl_xor(s, off);
        const float invS = 1.0f / s;
#pragma unroll
        for (int j = 0; j < 8; ++j) {
            float uu = e[j] * invS;
            ub[(size_t)row * R + tc + 32 * j] = uu;
            colp[j] += uu;
        }
    }

    // per-block column partial sums -> global atomic
#pragma unroll
    for (int j = 0; j < 8; ++j) colLDS[tr][tc + 32 * j] = colp[j];
    __syncthreads();
    {
        const int col = t;
        float sc = 0.f;
#pragma unroll
        for (int i = 0; i < 8; ++i) sc += colLDS[i][col];
        atomicAdd(&colsum[b * R + col], sc);
    }
}

// ---------------------------------------------------------------------------
// K2: v[b,n,r] = (sum_m x[b,m,n] * u[b,m,r]) / (colsum[b,r] + eps)
// grid (ksplit=8, ntile*rtile=8, B), block 256. 128x128 output tile,
// k-slab of 1024 rows, fp32 atomicAdd epilogue (v_out pre-zeroed).
// ---------------------------------------------------------------------------
__global__ __launch_bounds__(256) void ekm_vgemm(
    const float* __restrict__ x, const float* __restrict__ u,
    const float* __restrict__ colsum, float* __restrict__ v_out)
{
    __shared__ float Xs[16][132];   // [m_k][n]
    __shared__ float Us[16][132];   // [m_k][r]

    const int t     = threadIdx.x;
    const int kslab = blockIdx.x;        // 0..7
    const int ntile = blockIdx.y >> 1;   // 0..3
    const int rtile = blockIdx.y & 1;    // 0..1
    const int b     = blockIdx.z;

    const int n0 = ntile * 128;
    const int r0 = rtile * 128;
    const int m0 = kslab * 1024;

    const int tr = t >> 4;   // 0..15 (rows n0 + tr*8 .. +7)
    const int tc = t & 15;   // 0..15 (cols r0 + tc + 16*j)

    const int lml = t >> 4;        // load row within 16-chunk
    const int lf  = (t & 15) * 4;  // float offset 0..60

    const float* xb = x + ((size_t)b * M + m0) * N + n0;
    const float* ubase = u + ((size_t)b * M + m0) * R + r0;

    float acc[8][8];
#pragma unroll
    for (int i = 0; i < 8; ++i)
#pragma unroll
        for (int j = 0; j < 8; ++j) acc[i][j] = 0.f;

    for (int kb = 0; kb < 64; ++kb) {
        const float* xrow = xb + (size_t)(kb * 16 + lml) * N;
        const float* urow = ubase + (size_t)(kb * 16 + lml) * R;
        float4 xa = *(const float4*)(xrow + lf);
        float4 xc = *(const float4*)(xrow + lf + 64);
        float4 ua = *(const float4*)(urow + lf);
        float4 uc = *(const float4*)(urow + lf + 64);

        __syncthreads();
        *(float4*)&Xs[lml][lf]      = xa;
        *(float4*)&Xs[lml][lf + 64] = xc;
        *(float4*)&Us[lml][lf]      = ua;
        *(float4*)&Us[lml][lf + 64] = uc;
        __syncthreads();

#pragma unroll
        for (int k = 0; k < 16; ++k) {
            float a[8], bb[8];
            *(float4*)&a[0] = *(const float4*)&Xs[k][tr * 8];
            *(float4*)&a[4] = *(const float4*)&Xs[k][tr * 8 + 4];
#pragma unroll
            for (int j = 0; j < 8; ++j) bb[j] = Us[k][tc + 16 * j];
#pragma unroll
            for (int i = 0; i < 8; ++i)
#pragma unroll
                for (int j = 0; j < 8; ++j) acc[i][j] += a[i] * bb[j];
        }
    }

    float invs[8];
#pragma unroll
    for (int j = 0; j < 8; ++j)
        invs[j] = 1.0f / (colsum[b * R + r0 + tc + 16 * j] + EPSF);

#pragma unroll
    for (int i = 0; i < 8; ++i) {
        const int n = n0 + tr * 8 + i;
        float* vrow = v_out + ((size_t)b * N + n) * R + r0;
#pragma unroll
        for (int j = 0; j < 8; ++j)
            atomicAdd(&vrow[tc + 16 * j], acc[i][j] * invs[j]);
    }
}

extern "C" void kernel_launch(void* const* d_in, const int* in_sizes, int n_in,
                              void* d_out, int out_size, void* d_ws, size_t ws_size,
                              hipStream_t stream) {
    const float* x     = (const float*)d_in[0];
    const float* alpha = (const float*)d_in[1];
    const int*   inds  = (const int*)d_in[2];

    float* u_out  = (float*)d_out;                       // B*M*R
    float* v_out  = u_out + (size_t)B * M * R;           // B*N*R
    float* colsum = (float*)d_ws;                        // B*R

    hipMemsetAsync(colsum, 0, (size_t)B * R * sizeof(float), stream);
    hipMemsetAsync(v_out, 0, (size_t)B * N * R * sizeof(float), stream);

    dim3 g1(M / 64, B);
    ekm_dist_softmax<<<g1, 256, 0, stream>>>(x, alpha, inds, u_out, colsum);

    dim3 g2(8, 8, B);
    ekm_vgemm<<<g2, 256, 0, stream>>>(x, u_out, colsum, v_out);
}

// Round 2
// 432.637 us; speedup vs baseline: 1.5262x; 1.5262x over previous
//
#include <hip/hip_runtime.h>
#include <math.h>

#define B 8
#define M 8192
#define N 512
#define R 256
#define EPSF 1e-16f

typedef __attribute__((ext_vector_type(8))) short short8;
typedef __attribute__((ext_vector_type(4))) float f32x4;

__device__ __forceinline__ unsigned short bf16_rtn(float f) {
    unsigned int u = __float_as_uint(f);
    u += 0x7FFFu + ((u >> 16) & 1u);
    return (unsigned short)(u >> 16);
}

// ---------------------------------------------------------------------------
// P: x fp32 -> x_hi (bf16 RTN), x_lo (bf16 of residual), xT (transpose of hi),
//    x2 (exact fp32 row norms). grid (M/64, B), block 256.
// ---------------------------------------------------------------------------
__global__ __launch_bounds__(256) void ekm_prep(
    const float* __restrict__ x, unsigned short* __restrict__ x_hi,
    unsigned short* __restrict__ x_lo, unsigned short* __restrict__ xT,
    float* __restrict__ x2)
{
    __shared__ unsigned short Ts[64 * 264];
    __shared__ float x2s[64];
    const int t  = threadIdx.x;
    const int m0 = blockIdx.x * 64;
    const int b  = blockIdx.y;
    if (t < 64) x2s[t] = 0.f;
    __syncthreads();
    const float* xb = x + ((size_t)b * M + m0) * N;
    unsigned short* hib = x_hi + ((size_t)b * M + m0) * N;
    unsigned short* lob = x_lo + ((size_t)b * M + m0) * N;

    for (int h = 0; h < 2; ++h) {
#pragma unroll
        for (int i = 0; i < 16; ++i) {
            int flat = i * 256 + t;          // 0..4095 = 64 rows x 64 float4
            int row  = flat >> 6;
            int c4   = flat & 63;
            int col  = h * 256 + c4 * 4;
            float4 v = *(const float4*)(xb + (size_t)row * N + col);
            atomicAdd(&x2s[row], v.x * v.x + v.y * v.y + v.z * v.z + v.w * v.w);
            unsigned short h0 = bf16_rtn(v.x), h1 = bf16_rtn(v.y);
            unsigned short h2 = bf16_rtn(v.z), h3 = bf16_rtn(v.w);
            float l0 = v.x - __uint_as_float((unsigned)h0 << 16);
            float l1 = v.y - __uint_as_float((unsigned)h1 << 16);
            float l2 = v.z - __uint_as_float((unsigned)h2 << 16);
            float l3 = v.w - __uint_as_float((unsigned)h3 << 16);
            uint2 ph, pl;
            ph.x = (unsigned)h0 | ((unsigned)h1 << 16);
            ph.y = (unsigned)h2 | ((unsigned)h3 << 16);
            pl.x = (unsigned)bf16_rtn(l0) | ((unsigned)bf16_rtn(l1) << 16);
            pl.y = (unsigned)bf16_rtn(l2) | ((unsigned)bf16_rtn(l3) << 16);
            *(uint2*)(hib + (size_t)row * N + col) = ph;
            *(uint2*)(lob + (size_t)row * N + col) = pl;
            *(uint2*)&Ts[row * 264 + c4 * 4] = ph;
        }
        __syncthreads();
        {   // transpose out: this thread owns column n
            int n = h * 256 + t;
            unsigned short* xTb = xT + ((size_t)b * N + n) * M + m0;
#pragma unroll
            for (int m4 = 0; m4 < 16; ++m4) {
                unsigned short v0 = Ts[(m4 * 4 + 0) * 264 + t];
                unsigned short v1 = Ts[(m4 * 4 + 1) * 264 + t];
                unsigned short v2 = Ts[(m4 * 4 + 2) * 264 + t];
                unsigned short v3 = Ts[(m4 * 4 + 3) * 264 + t];
                uint2 p;
                p.x = (unsigned)v0 | ((unsigned)v1 << 16);
                p.y = (unsigned)v2 | ((unsigned)v3 << 16);
                *(uint2*)(xTb + m4 * 4) = p;
            }
        }
        __syncthreads();
    }
    if (t < 64) x2[(size_t)b * M + m0 + t] = x2s[t];
}

// ---------------------------------------------------------------------------
// K1: split-bf16 MFMA distances + fused softmax.
// grid (M/64, B), block 256 (4 waves). Block tile 64m x 256r; wave w owns
// r-range [w*64, w*64+64) as 4x4 tiles of 16x16x32 MFMA.
// acc += Ah*Bh + Ah*Bl + Al*Bh  (~16-bit mantissa xv).
// Outputs: u fp32 [m][r], uT bf16 [r][m], colsum (atomic).
// ---------------------------------------------------------------------------
__global__ __launch_bounds__(256) void ekm_k1(
    const unsigned short* __restrict__ x_hi, const unsigned short* __restrict__ x_lo,
    const float* __restrict__ alpha_p, const int* __restrict__ inds,
    const float* __restrict__ x2, float* __restrict__ u_out,
    unsigned short* __restrict__ uT, float* __restrict__ colsum)
{
    __shared__ unsigned short Ah[64 * 40], Al[64 * 40];
    __shared__ unsigned short Bh[256 * 40], Bl[256 * 40];
    __shared__ float x2s[64], v2s[256], redm[256], reds[256];

    const int t    = threadIdx.x;
    const int b    = blockIdx.y;
    const int m0   = blockIdx.x * 64;
    const int w    = t >> 6;
    const int lane = t & 63;
    const int ln   = lane & 15;
    const int q    = lane >> 4;

    if (t < 64) x2s[t] = x2[(size_t)b * M + m0 + t];
    v2s[t] = x2[(size_t)b * M + inds[t]];

    const int arow = t >> 2;     // 0..63
    const int ach  = t & 3;      // 0..3 (16B chunk)
    int cind[4];
#pragma unroll
    for (int p = 0; p < 4; ++p) cind[p] = inds[arow + p * 64];

    const unsigned short* hibase = x_hi + (size_t)b * M * N;
    const unsigned short* lobase = x_lo + (size_t)b * M * N;

    f32x4 acc[4][4];
#pragma unroll
    for (int i = 0; i < 4; ++i)
#pragma unroll
        for (int j = 0; j < 4; ++j) acc[i][j] = (f32x4)0.f;

    for (int k0 = 0; k0 < N; k0 += 32) {
        short8 va_h = *(const short8*)(hibase + (size_t)(m0 + arow) * N + k0 + ach * 8);
        short8 va_l = *(const short8*)(lobase + (size_t)(m0 + arow) * N + k0 + ach * 8);
        short8 vb_h[4], vb_l[4];
#pragma unroll
        for (int p = 0; p < 4; ++p) {
            vb_h[p] = *(const short8*)(hibase + (size_t)cind[p] * N + k0 + ach * 8);
            vb_l[p] = *(const short8*)(lobase + (size_t)cind[p] * N + k0 + ach * 8);
        }
        __syncthreads();
        *(short8*)&Ah[arow * 40 + ach * 8] = va_h;
        *(short8*)&Al[arow * 40 + ach * 8] = va_l;
#pragma unroll
        for (int p = 0; p < 4; ++p) {
            int r = arow + p * 64;
            *(short8*)&Bh[r * 40 + ach * 8] = vb_h[p];
            *(short8*)&Bl[r * 40 + ach * 8] = vb_l[p];
        }
        __syncthreads();

        short8 ah[4], al[4], bh[4], bl[4];
#pragma unroll
        for (int mi = 0; mi < 4; ++mi) {
            ah[mi] = *(const short8*)&Ah[(mi * 16 + ln) * 40 + q * 8];
            al[mi] = *(const short8*)&Al[(mi * 16 + ln) * 40 + q * 8];
        }
#pragma unroll
        for (int rj = 0; rj < 4; ++rj) {
            bh[rj] = *(const short8*)&Bh[(w * 64 + rj * 16 + ln) * 40 + q * 8];
            bl[rj] = *(const short8*)&Bl[(w * 64 + rj * 16 + ln) * 40 + q * 8];
        }
#pragma unroll
        for (int mi = 0; mi < 4; ++mi)
#pragma unroll
            for (int rj = 0; rj < 4; ++rj) {
                acc[mi][rj] = __builtin_amdgcn_mfma_f32_16x16x32_bf16(ah[mi], bh[rj], acc[mi][rj], 0, 0, 0);
                acc[mi][rj] = __builtin_amdgcn_mfma_f32_16x16x32_bf16(ah[mi], bl[rj], acc[mi][rj], 0, 0, 0);
                acc[mi][rj] = __builtin_amdgcn_mfma_f32_16x16x32_bf16(al[mi], bh[rj], acc[mi][rj], 0, 0, 0);
            }
    }

    // ---- epilogue: d = relu(x2 - 2xv + v2), softmax over r=0..255 per row m
    const float ia = 1.4426950408889634f / alpha_p[0];   // log2e / alpha

#pragma unroll
    for (int mi = 0; mi < 4; ++mi) {
        f32x4 x2v = *(const f32x4*)&x2s[mi * 16 + q * 4];
#pragma unroll
        for (int rj = 0; rj < 4; ++rj) {
            float v2c = v2s[w * 64 + rj * 16 + ln];
#pragma unroll
            for (int reg = 0; reg < 4; ++reg) {
                float d = x2v[reg] - 2.f * acc[mi][rj][reg] + v2c;
                acc[mi][rj][reg] = fmaxf(d, 0.f);
            }
        }
    }
    // per-row min (this wave's 64 r)
    float rmin[4][4];
#pragma unroll
    for (int mi = 0; mi < 4; ++mi)
#pragma unroll
        for (int reg = 0; reg < 4; ++reg) {
            float v = fminf(fminf(acc[mi][0][reg], acc[mi][1][reg]),
                            fminf(acc[mi][2][reg], acc[mi][3][reg]));
            v = fminf(v, __shfl_xor(v, 1));
            v = fminf(v, __shfl_xor(v, 2));
            v = fminf(v, __shfl_xor(v, 4));
            v = fminf(v, __shfl_xor(v, 8));
            rmin[mi][reg] = v;
        }
    if (ln == 0) {
#pragma unroll
        for (int mi = 0; mi < 4; ++mi)
#pragma unroll
            for (int reg = 0; reg < 4; ++reg)
                redm[w * 64 + mi * 16 + q * 4 + reg] = rmin[mi][reg];
    }
    __syncthreads();
#pragma unroll
    for (int mi = 0; mi < 4; ++mi)
#pragma unroll
        for (int reg = 0; reg < 4; ++reg) {
            int m = mi * 16 + q * 4 + reg;
            rmin[mi][reg] = fminf(fminf(redm[m], redm[64 + m]),
                                  fminf(redm[128 + m], redm[192 + m]));
        }
    // exp + per-row sum
    float rsum[4][4];
#pragma unroll
    for (int mi = 0; mi < 4; ++mi)
#pragma unroll
        for (int reg = 0; reg < 4; ++reg) rsum[mi][reg] = 0.f;
#pragma unroll
    for (int mi = 0; mi < 4; ++mi)
#pragma unroll
        for (int rj = 0; rj < 4; ++rj)
#pragma unroll
            for (int reg = 0; reg < 4; ++reg) {
                float e = exp2f((rmin[mi][reg] - acc[mi][rj][reg]) * ia);
                acc[mi][rj][reg] = e;
                rsum[mi][reg] += e;
            }
#pragma unroll
    for (int mi = 0; mi < 4; ++mi)
#pragma unroll
        for (int reg = 0; reg < 4; ++reg) {
            float v = rsum[mi][reg];
            v += __shfl_xor(v, 1);
            v += __shfl_xor(v, 2);
            v += __shfl_xor(v, 4);
            v += __shfl_xor(v, 8);
            rsum[mi][reg] = v;
        }
    if (ln == 0) {
#pragma unroll
        for (int mi = 0; mi < 4; ++mi)
#pragma unroll
            for (int reg = 0; reg < 4; ++reg)
                reds[w * 64 + mi * 16 + q * 4 + reg] = rsum[mi][reg];
    }
    __syncthreads();
    float invS[4][4];
#pragma unroll
    for (int mi = 0; mi < 4; ++mi)
#pragma unroll
        for (int reg = 0; reg < 4; ++reg) {
            int m = mi * 16 + q * 4 + reg;
            invS[mi][reg] = 1.f / (reds[m] + reds[64 + m] + reds[128 + m] + reds[192 + m]);
        }

    float* ub = u_out + ((size_t)b * M + m0) * R;
    unsigned short* uTb = uT + (size_t)b * R * M;
    float csum[4] = {0.f, 0.f, 0.f, 0.f};
#pragma unroll
    for (int mi = 0; mi < 4; ++mi)
#pragma unroll
        for (int rj = 0; rj < 4; ++rj) {
            int rr = w * 64 + rj * 16 + ln;
            unsigned short pk[4];
#pragma unroll
            for (int reg = 0; reg < 4; ++reg) {
                float uu = acc[mi][rj][reg] * invS[mi][reg];
                ub[(size_t)(mi * 16 + q * 4 + reg) * R + rr] = uu;
                csum[rj] += uu;
                pk[reg] = bf16_rtn(uu);
            }
            uint2 p;
            p.x = (unsigned)pk[0] | ((unsigned)pk[1] << 16);
            p.y = (unsigned)pk[2] | ((unsigned)pk[3] << 16);
            *(uint2*)(uTb + (size_t)rr * M + m0 + mi * 16 + q * 4) = p;
        }
#pragma unroll
    for (int rj = 0; rj < 4; ++rj) {
        float v = csum[rj];
        v += __shfl_xor(v, 16);
        v += __shfl_xor(v, 32);
        if (q == 0) atomicAdd(&colsum[b * R + w * 64 + rj * 16 + ln], v);
    }
}

// ---------------------------------------------------------------------------
// K2: v[n][r] = (sum_m xT[n][m] * uT[r][m]) / (colsum[r]+eps), plain bf16 MFMA.
// grid (8 = 4n*2r tiles, 8 k-slabs, B), block 256 (4 waves, 2x2 of 64x64).
// fp32 atomicAdd epilogue into pre-zeroed v.
// ---------------------------------------------------------------------------
__global__ __launch_bounds__(256) void ekm_k2(
    const unsigned short* __restrict__ xT, const unsigned short* __restrict__ uT,
    const float* __restrict__ colsum, float* __restrict__ v_out)
{
    __shared__ unsigned short As[128 * 40], Bs[128 * 40];
    const int t  = threadIdx.x;
    const int nt = blockIdx.x >> 1, rt = blockIdx.x & 1;
    const int kslab = blockIdx.y;
    const int b  = blockIdx.z;
    const int n0 = nt * 128, r0 = rt * 128;
    const int w  = t >> 6, lane = t & 63, ln = lane & 15, q = lane >> 4;
    const int wn = w >> 1, wr = w & 1;
    const int arow = t >> 2, ach = t & 3;

    const unsigned short* xTb = xT + ((size_t)b * N + n0) * M;
    const unsigned short* uTb = uT + ((size_t)b * R + r0) * M;

    f32x4 acc[4][4];
#pragma unroll
    for (int i = 0; i < 4; ++i)
#pragma unroll
        for (int j = 0; j < 4; ++j) acc[i][j] = (f32x4)0.f;

    const int kbeg = kslab * 1024;
    for (int k0 = kbeg; k0 < kbeg + 1024; k0 += 32) {
        short8 va[2], vb[2];
#pragma unroll
        for (int i = 0; i < 2; ++i) {
            int row = arow + i * 64;
            va[i] = *(const short8*)(xTb + (size_t)row * M + k0 + ach * 8);
            vb[i] = *(const short8*)(uTb + (size_t)row * M + k0 + ach * 8);
        }
        __syncthreads();
#pragma unroll
        for (int i = 0; i < 2; ++i) {
            int row = arow + i * 64;
            *(short8*)&As[row * 40 + ach * 8] = va[i];
            *(short8*)&Bs[row * 40 + ach * 8] = vb[i];
        }
        __syncthreads();
        short8 af[4], bf[4];
#pragma unroll
        for (int ni = 0; ni < 4; ++ni)
            af[ni] = *(const short8*)&As[(wn * 64 + ni * 16 + ln) * 40 + q * 8];
#pragma unroll
        for (int rj = 0; rj < 4; ++rj)
            bf[rj] = *(const short8*)&Bs[(wr * 64 + rj * 16 + ln) * 40 + q * 8];
#pragma unroll
        for (int ni = 0; ni < 4; ++ni)
#pragma unroll
            for (int rj = 0; rj < 4; ++rj)
                acc[ni][rj] = __builtin_amdgcn_mfma_f32_16x16x32_bf16(af[ni], bf[rj], acc[ni][rj], 0, 0, 0);
    }

    float invs[4];
#pragma unroll
    for (int rj = 0; rj < 4; ++rj)
        invs[rj] = 1.f / (colsum[b * R + r0 + wr * 64 + rj * 16 + ln] + EPSF);

#pragma unroll
    for (int ni = 0; ni < 4; ++ni)
#pragma unroll
        for (int rj = 0; rj < 4; ++rj)
#pragma unroll
            for (int reg = 0; reg < 4; ++reg) {
                size_t n = (size_t)n0 + wn * 64 + ni * 16 + q * 4 + reg;
                int rr = r0 + wr * 64 + rj * 16 + ln;
                atomicAdd(v_out + ((size_t)b * N + n) * R + rr,
                          acc[ni][rj][reg] * invs[rj]);
            }
}

// ---------------------------------------------------------------------------
// Fallback (round-1 fp32 VALU kernels) — used only if ws_size is too small.
// ---------------------------------------------------------------------------
__global__ __launch_bounds__(256) void ekm_dist_softmax_fb(
    const float* __restrict__ x, const float* __restrict__ alpha_p,
    const int* __restrict__ inds, float* __restrict__ u_out,
    float* __restrict__ colsum)
{
    __shared__ float As_[16][68];
    __shared__ float Bs_[16][257];
    __shared__ float x2s[64];
    __shared__ float v2s[256];
    __shared__ float colLDS[8][256];

    const int t    = threadIdx.x;
    const int b    = blockIdx.y;
    const int mt   = blockIdx.x * 64;
    const int lrow = t >> 2;
    const int kq   = (t & 3) * 4;
    int cind[4];
#pragma unroll
    for (int p = 0; p < 4; ++p) cind[p] = inds[lrow + 64 * p];
    const float* xb = x + (size_t)b * M * N;
    float acc[8][8];
#pragma unroll
    for (int i = 0; i < 8; ++i)
#pragma unroll
        for (int j = 0; j < 8; ++j) acc[i][j] = 0.f;
    float x2part = 0.f;
    float v2part[4] = {0.f, 0.f, 0.f, 0.f};
    const int tr = t >> 5;
    const int tc = t & 31;
    for (int k0 = 0; k0 < N; k0 += 16) {
        float4 av = *(const float4*)(xb + (size_t)(mt + lrow) * N + k0 + kq);
        float4 bv[4];
#pragma unroll
        for (int p = 0; p < 4; ++p)
            bv[p] = *(const float4*)(xb + (size_t)cind[p] * N + k0 + kq);
        __syncthreads();
        As_[kq + 0][lrow] = av.x; As_[kq + 1][lrow] = av.y;
        As_[kq + 2][lrow] = av.z; As_[kq + 3][lrow] = av.w;
        x2part += av.x * av.x + av.y * av.y + av.z * av.z + av.w * av.w;
#pragma unroll
        for (int p = 0; p < 4; ++p) {
            int r = lrow + 64 * p;
            Bs_[kq + 0][r] = bv[p].x; Bs_[kq + 1][r] = bv[p].y;
            Bs_[kq + 2][r] = bv[p].z; Bs_[kq + 3][r] = bv[p].w;
            v2part[p] += bv[p].x * bv[p].x + bv[p].y * bv[p].y
                       + bv[p].z * bv[p].z + bv[p].w * bv[p].w;
        }
        __syncthreads();
#pragma unroll
        for (int k = 0; k < 16; ++k) {
            float a[8], bb[8];
            *(float4*)&a[0] = *(const float4*)&As_[k][tr * 8];
            *(float4*)&a[4] = *(const float4*)&As_[k][tr * 8 + 4];
#pragma unroll
            for (int j = 0; j < 8; ++j) bb[j] = Bs_[k][tc + 32 * j];
#pragma unroll
            for (int i = 0; i < 8; ++i)
#pragma unroll
                for (int j = 0; j < 8; ++j) acc[i][j] += a[i] * bb[j];
        }
    }
    x2part += __shfl_xor(x2part, 1);
    x2part += __shfl_xor(x2part, 2);
    if ((t & 3) == 0) x2s[lrow] = x2part;
#pragma unroll
    for (int p = 0; p < 4; ++p) {
        float v = v2part[p];
        v += __shfl_xor(v, 1);
        v += __shfl_xor(v, 2);
        if ((t & 3) == 0) v2s[lrow + 64 * p] = v;
    }
    __syncthreads();
    const float inv_alpha = 1.0f / alpha_p[0];
    float v2c[8];
#pragma unroll
    for (int j = 0; j < 8; ++j) v2c[j] = v2s[tc + 32 * j];
    float colp[8] = {0.f, 0.f, 0.f, 0.f, 0.f, 0.f, 0.f, 0.f};
    float* ub = u_out + ((size_t)b * M + mt) * R;
#pragma unroll
    for (int i = 0; i < 8; ++i) {
        const int row = tr * 8 + i;
        const float x2v = x2s[row];
        float d[8];
        float dmin = 3.4e38f;
#pragma unroll
        for (int j = 0; j < 8; ++j) {
            float dd = x2v - 2.f * acc[i][j] + v2c[j];
            dd = fmaxf(dd, 0.f);
            d[j] = dd;
            dmin = fminf(dmin, dd);
        }
#pragma unroll
        for (int off = 1; off < 32; off <<= 1)
            dmin = fminf(dmin, __shfl_xor(dmin, off));
        float e[8];
        float s = 0.f;
#pragma unroll
        for (int j = 0; j < 8; ++j) {
            e[j] = expf((dmin - d[j]) * inv_alpha);
            s += e[j];
        }
#pragma unroll
        for (int off = 1; off < 32; off <<= 1) s += __shfl_xor(s, off);
        const float invSf = 1.0f / s;
#pragma unroll
        for (int j = 0; j < 8; ++j) {
            float uu = e[j] * invSf;
            ub[(size_t)row * R + tc + 32 * j] = uu;
            colp[j] += uu;
        }
    }
#pragma unroll
    for (int j = 0; j < 8; ++j) colLDS[tr][tc + 32 * j] = colp[j];
    __syncthreads();
    {
        const int col = t;
        float sc = 0.f;
#pragma unroll
        for (int i = 0; i < 8; ++i) sc += colLDS[i][col];
        atomicAdd(&colsum[b * R + col], sc);
    }
}

__global__ __launch_bounds__(256) void ekm_vgemm_fb(
    const float* __restrict__ x, const float* __restrict__ u,
    const float* __restrict__ colsum, float* __restrict__ v_out)
{
    __shared__ float Xs[16][132];
    __shared__ float Us[16][132];
    const int t     = threadIdx.x;
    const int kslab = blockIdx.x;
    const int ntile = blockIdx.y >> 1;
    const int rtile = blockIdx.y & 1;
    const int b     = blockIdx.z;
    const int n0 = ntile * 128;
    const int r0 = rtile * 128;
    const int m0 = kslab * 1024;
    const int tr = t >> 4;
    const int tc = t & 15;
    const int lml = t >> 4;
    const int lf  = (t & 15) * 4;
    const float* xb = x + ((size_t)b * M + m0) * N + n0;
    const float* ubase = u + ((size_t)b * M + m0) * R + r0;
    float acc[8][8];
#pragma unroll
    for (int i = 0; i < 8; ++i)
#pragma unroll
        for (int j = 0; j < 8; ++j) acc[i][j] = 0.f;
    for (int kb = 0; kb < 64; ++kb) {
        const float* xrow = xb + (size_t)(kb * 16 + lml) * N;
        const float* urow = ubase + (size_t)(kb * 16 + lml) * R;
        float4 xa = *(const float4*)(xrow + lf);
        float4 xc = *(const float4*)(xrow + lf + 64);
        float4 ua = *(const float4*)(urow + lf);
        float4 uc = *(const float4*)(urow + lf + 64);
        __syncthreads();
        *(float4*)&Xs[lml][lf]      = xa;
        *(float4*)&Xs[lml][lf + 64] = xc;
        *(float4*)&Us[lml][lf]      = ua;
        *(float4*)&Us[lml][lf + 64] = uc;
        __syncthreads();
#pragma unroll
        for (int k = 0; k < 16; ++k) {
            float a[8], bb[8];
            *(float4*)&a[0] = *(const float4*)&Xs[k][tr * 8];
            *(float4*)&a[4] = *(const float4*)&Xs[k][tr * 8 + 4];
#pragma unroll
            for (int j = 0; j < 8; ++j) bb[j] = Us[k][tc + 16 * j];
#pragma unroll
            for (int i = 0; i < 8; ++i)
#pragma unroll
                for (int j = 0; j < 8; ++j) acc[i][j] += a[i] * bb[j];
        }
    }
    float invs[8];
#pragma unroll
    for (int j = 0; j < 8; ++j)
        invs[j] = 1.0f / (colsum[b * R + r0 + tc + 16 * j] + EPSF);
#pragma unroll
    for (int i = 0; i < 8; ++i) {
        const int n = n0 + tr * 8 + i;
        float* vrow = v_out + ((size_t)b * N + n) * R + r0;
#pragma unroll
        for (int j = 0; j < 8; ++j)
            atomicAdd(&vrow[tc + 16 * j], acc[i][j] * invs[j]);
    }
}

extern "C" void kernel_launch(void* const* d_in, const int* in_sizes, int n_in,
                              void* d_out, int out_size, void* d_ws, size_t ws_size,
                              hipStream_t stream) {
    const float* x     = (const float*)d_in[0];
    const float* alpha = (const float*)d_in[1];
    const int*   inds  = (const int*)d_in[2];

    float* u_out = (float*)d_out;                      // B*M*R fp32
    float* v_out = u_out + (size_t)B * M * R;          // B*N*R fp32

    const size_t S1 = (size_t)B * M * N * 2;           // bf16 x-sized array
    const size_t S2 = (size_t)B * R * M * 2;           // bf16 uT
    const size_t need = 3 * S1 + S2 + (size_t)B * M * 4 + (size_t)B * R * 4;

    if (ws_size >= need) {
        char* ws = (char*)d_ws;
        unsigned short* x_hi = (unsigned short*)ws;
        unsigned short* x_lo = (unsigned short*)(ws + S1);
        unsigned short* xT   = (unsigned short*)(ws + 2 * S1);
        unsigned short* uT   = (unsigned short*)(ws + 3 * S1);
        float* x2     = (float*)(ws + 3 * S1 + S2);
        float* colsum = (float*)(ws + 3 * S1 + S2 + (size_t)B * M * 4);

        hipMemsetAsync(colsum, 0, (size_t)B * R * sizeof(float), stream);
        hipMemsetAsync(v_out, 0, (size_t)B * N * R * sizeof(float), stream);

        dim3 gp(M / 64, B);
        ekm_prep<<<gp, 256, 0, stream>>>(x, x_hi, x_lo, xT, x2);

        dim3 g1(M / 64, B);
        ekm_k1<<<g1, 256, 0, stream>>>(x_hi, x_lo, alpha, inds, x2, u_out, uT, colsum);

        dim3 g2(8, 8, B);
        ekm_k2<<<g2, 256, 0, stream>>>(xT, uT, colsum, v_out);
    } else {
        float* colsum = (float*)d_ws;
        hipMemsetAsync(colsum, 0, (size_t)B * R * sizeof(float), stream);
        hipMemsetAsync(v_out, 0, (size_t)B * N * R * sizeof(float), stream);
        dim3 g1(M / 64, B);
        ekm_dist_softmax_fb<<<g1, 256, 0, stream>>>(x, alpha, inds, u_out, colsum);
        dim3 g2(8, 8, B);
        ekm_vgemm_fb<<<g2, 256, 0, stream>>>(x, u_out, colsum, v_out);
    }
}

// Round 3
// 358.969 us; speedup vs baseline: 1.8394x; 1.2052x over previous
//
#include <hip/hip_runtime.h>
#include <math.h>

#define B 8
#define M 8192
#define N 512
#define R 256
#define EPSF 1e-16f

typedef __attribute__((ext_vector_type(8))) short short8;
typedef __attribute__((ext_vector_type(16))) float f32x16;

__device__ __forceinline__ unsigned short bf16_rtn(float f) {
    unsigned int u = __float_as_uint(f);
    u += 0x7FFFu + ((u >> 16) & 1u);
    return (unsigned short)(u >> 16);
}

// async global->LDS, 16B per lane. LDS side must be wave-uniform base + lane*16.
__device__ __forceinline__ void gll16(const unsigned short* g, unsigned short* l) {
    __builtin_amdgcn_global_load_lds(
        (const __attribute__((address_space(1))) unsigned int*)g,
        (__attribute__((address_space(3))) unsigned int*)l, 16, 0, 0);
}

// ---------------------------------------------------------------------------
// Kc: gather centers x[b, inds, :] -> c_hi/c_lo (split bf16) + exact fp32 v2.
// grid (16, B), block 256. Each block: 16 center rows.
// ---------------------------------------------------------------------------
__global__ __launch_bounds__(256) void ekm_kc(
    const float* __restrict__ x, const int* __restrict__ inds,
    unsigned short* __restrict__ c_hi, unsigned short* __restrict__ c_lo,
    float* __restrict__ v2g)
{
    const int t = threadIdx.x, b = blockIdx.y;
    const int r = blockIdx.x * 16 + (t >> 4);
    const int seg = (t & 15) * 32;
    const float* src = x + ((size_t)b * M + inds[r]) * N + seg;
    unsigned short* hd = c_hi + ((size_t)b * R + r) * 512 + seg;
    unsigned short* ld = c_lo + ((size_t)b * R + r) * 512 + seg;
    float vp = 0.f;
#pragma unroll
    for (int c = 0; c < 4; ++c) {
        float4 f0 = *(const float4*)(src + c * 8);
        float4 f1 = *(const float4*)(src + c * 8 + 4);
        float av[8] = {f0.x, f0.y, f0.z, f0.w, f1.x, f1.y, f1.z, f1.w};
        unsigned ph[4], pl[4];
#pragma unroll
        for (int j = 0; j < 4; ++j) {
            vp += av[2*j] * av[2*j] + av[2*j+1] * av[2*j+1];
            unsigned short h0 = bf16_rtn(av[2*j]), h1 = bf16_rtn(av[2*j+1]);
            float r0 = av[2*j]   - __uint_as_float((unsigned)h0 << 16);
            float r1 = av[2*j+1] - __uint_as_float((unsigned)h1 << 16);
            ph[j] = (unsigned)h0 | ((unsigned)h1 << 16);
            pl[j] = (unsigned)bf16_rtn(r0) | ((unsigned)bf16_rtn(r1) << 16);
        }
        *(uint4*)(hd + c * 8) = make_uint4(ph[0], ph[1], ph[2], ph[3]);
        *(uint4*)(ld + c * 8) = make_uint4(pl[0], pl[1], pl[2], pl[3]);
    }
    vp += __shfl_xor(vp, 1); vp += __shfl_xor(vp, 2);
    vp += __shfl_xor(vp, 4); vp += __shfl_xor(vp, 8);
    if ((t & 15) == 0) v2g[b * R + r] = vp;
}

// ---------------------------------------------------------------------------
// K1: split-bf16 32x32x16 MFMA distances + fused softmax, x read fp32 inline.
// grid (M/64, B), block 256 (4 waves). Block tile 64m x 256r; wave w owns
// r in [w*64, w*64+64) as 2x2 tiles of 32x32. Also emits xT (bf16) slabs
// and uT (bf16), colsum (atomic).
// ---------------------------------------------------------------------------
__global__ __launch_bounds__(256, 3) void ekm_k1(
    const float* __restrict__ x, const float* __restrict__ alpha_p,
    const unsigned short* __restrict__ c_hi, const unsigned short* __restrict__ c_lo,
    const float* __restrict__ v2g, float* __restrict__ u_out,
    unsigned short* __restrict__ uT, unsigned short* __restrict__ xT,
    float* __restrict__ colsum)
{
    __shared__ unsigned short Ah[64 * 40], Al[64 * 40];   // padded, VGPR-staged
    __shared__ unsigned short Bh[256 * 32], Bl[256 * 32]; // unpadded (gll)
    __shared__ float x2s[64];
    __shared__ float redm[4][64], reds[4][64];

    const int t = threadIdx.x;
    const int b = blockIdx.y;
    const int m0 = blockIdx.x * 64;
    const int w = t >> 6, l = t & 63, col = l & 31, h5 = l >> 5;
    const int arow = t >> 2, kch = t & 3;

    const float* ax = x + ((size_t)b * M + m0 + arow) * N + kch * 8;
    const unsigned short* bhs = c_hi + ((size_t)b * R + (t >> 2)) * 512 + (t & 3) * 8;
    const unsigned short* bls = c_lo + ((size_t)b * R + (t >> 2)) * 512 + (t & 3) * 8;

    f32x16 acc[2][2];
    acc[0][0] = (f32x16)0.f; acc[0][1] = (f32x16)0.f;
    acc[1][0] = (f32x16)0.f; acc[1][1] = (f32x16)0.f;

    float x2p = 0.f;

    for (int k0 = 0; k0 < N; k0 += 32) {
        float4 a0 = *(const float4*)(ax + k0);
        float4 a1 = *(const float4*)(ax + k0 + 4);
        x2p += a0.x*a0.x + a0.y*a0.y + a0.z*a0.z + a0.w*a0.w
             + a1.x*a1.x + a1.y*a1.y + a1.z*a1.z + a1.w*a1.w;
        float av[8] = {a0.x, a0.y, a0.z, a0.w, a1.x, a1.y, a1.z, a1.w};
        unsigned ph[4], pl[4];
#pragma unroll
        for (int j = 0; j < 4; ++j) {
            unsigned short h0 = bf16_rtn(av[2*j]), h1 = bf16_rtn(av[2*j+1]);
            float r0 = av[2*j]   - __uint_as_float((unsigned)h0 << 16);
            float r1 = av[2*j+1] - __uint_as_float((unsigned)h1 << 16);
            ph[j] = (unsigned)h0 | ((unsigned)h1 << 16);
            pl[j] = (unsigned)bf16_rtn(r0) | ((unsigned)bf16_rtn(r1) << 16);
        }
        __syncthreads();   // previous tile fully consumed
#pragma unroll
        for (int i = 0; i < 4; ++i) {
            gll16(bhs + k0 + i * (64 * 512), Bh + i * 2048 + t * 8);
            gll16(bls + k0 + i * (64 * 512), Bl + i * 2048 + t * 8);
        }
        *(uint4*)&Ah[arow * 40 + kch * 8] = make_uint4(ph[0], ph[1], ph[2], ph[3]);
        *(uint4*)&Al[arow * 40 + kch * 8] = make_uint4(pl[0], pl[1], pl[2], pl[3]);
        __syncthreads();   // drains gll (vmcnt) + LDS writes

        // xT slab: [k0+kk][m0..m0+63], coalesced 16B stores
        {
            int kk = t >> 3, ms = (t & 7) * 8;
            unsigned q0 = (unsigned)Ah[(ms+0)*40+kk] | ((unsigned)Ah[(ms+1)*40+kk] << 16);
            unsigned q1 = (unsigned)Ah[(ms+2)*40+kk] | ((unsigned)Ah[(ms+3)*40+kk] << 16);
            unsigned q2 = (unsigned)Ah[(ms+4)*40+kk] | ((unsigned)Ah[(ms+5)*40+kk] << 16);
            unsigned q3 = (unsigned)Ah[(ms+6)*40+kk] | ((unsigned)Ah[(ms+7)*40+kk] << 16);
            *(uint4*)(xT + ((size_t)b * N + k0 + kk) * M + m0 + ms) = make_uint4(q0, q1, q2, q3);
        }

#pragma unroll
        for (int half = 0; half < 2; ++half) {
            short8 ah[2], al2[2], bh[2], bl2[2];
#pragma unroll
            for (int tm = 0; tm < 2; ++tm) {
                ah[tm]  = *(const short8*)&Ah[(tm*32 + col) * 40 + half*16 + h5*8];
                al2[tm] = *(const short8*)&Al[(tm*32 + col) * 40 + half*16 + h5*8];
            }
#pragma unroll
            for (int tr = 0; tr < 2; ++tr) {
                bh[tr]  = *(const short8*)&Bh[(w*64 + tr*32 + col) * 32 + half*16 + h5*8];
                bl2[tr] = *(const short8*)&Bl[(w*64 + tr*32 + col) * 32 + half*16 + h5*8];
            }
#pragma unroll
            for (int tm = 0; tm < 2; ++tm)
#pragma unroll
            for (int tr = 0; tr < 2; ++tr) {
                acc[tm][tr] = __builtin_amdgcn_mfma_f32_32x32x16_bf16(ah[tm],  bh[tr],  acc[tm][tr], 0, 0, 0);
                acc[tm][tr] = __builtin_amdgcn_mfma_f32_32x32x16_bf16(ah[tm],  bl2[tr], acc[tm][tr], 0, 0, 0);
                acc[tm][tr] = __builtin_amdgcn_mfma_f32_32x32x16_bf16(al2[tm], bh[tr],  acc[tm][tr], 0, 0, 0);
            }
        }
    }

    // ---- epilogue ----
    x2p += __shfl_xor(x2p, 1);
    x2p += __shfl_xor(x2p, 2);
    if (kch == 0) x2s[arow] = x2p;
    __syncthreads();

    const float ia = 1.4426950408889634f / alpha_p[0];  // log2(e)/alpha
    float v2c[2];
#pragma unroll
    for (int tr = 0; tr < 2; ++tr)
        v2c[tr] = v2g[b * R + w * 64 + tr * 32 + col];

    // d = relu(x2 - 2xv + v2); wave-local row min; stage to LDS
#pragma unroll
    for (int tm = 0; tm < 2; ++tm)
#pragma unroll
    for (int reg = 0; reg < 16; ++reg) {
        int rowl = (reg & 3) + 8 * (reg >> 2) + 4 * h5;
        float x2v = x2s[tm * 32 + rowl];
        float mn;
#pragma unroll
        for (int tr = 0; tr < 2; ++tr) {
            float d = x2v - 2.f * acc[tm][tr][reg] + v2c[tr];
            d = fmaxf(d, 0.f);
            acc[tm][tr][reg] = d;
            mn = (tr == 0) ? d : fminf(mn, d);
        }
        mn = fminf(mn, __shfl_xor(mn, 1));
        mn = fminf(mn, __shfl_xor(mn, 2));
        mn = fminf(mn, __shfl_xor(mn, 4));
        mn = fminf(mn, __shfl_xor(mn, 8));
        mn = fminf(mn, __shfl_xor(mn, 16));
        if (col == 0) redm[w][tm * 32 + rowl] = mn;
    }
    __syncthreads();

    // exp + row sum
#pragma unroll
    for (int tm = 0; tm < 2; ++tm)
#pragma unroll
    for (int reg = 0; reg < 16; ++reg) {
        int m = tm * 32 + (reg & 3) + 8 * (reg >> 2) + 4 * h5;
        float mn = fminf(fminf(redm[0][m], redm[1][m]), fminf(redm[2][m], redm[3][m]));
        float s = 0.f;
#pragma unroll
        for (int tr = 0; tr < 2; ++tr) {
            float e = exp2f((mn - acc[tm][tr][reg]) * ia);
            acc[tm][tr][reg] = e;
            s += e;
        }
        s += __shfl_xor(s, 1); s += __shfl_xor(s, 2); s += __shfl_xor(s, 4);
        s += __shfl_xor(s, 8); s += __shfl_xor(s, 16);
        if (col == 0) reds[w][m] = s;
    }
    __syncthreads();

    // normalize, write u (fp32), accumulate colsum, pack uT (bf16)
    float* ub = u_out + ((size_t)b * M + m0) * R + w * 64;
    float cs[2] = {0.f, 0.f};
#pragma unroll
    for (int tm = 0; tm < 2; ++tm)
#pragma unroll
    for (int reg = 0; reg < 16; ++reg) {
        int rowl = (reg & 3) + 8 * (reg >> 2) + 4 * h5;
        int m = tm * 32 + rowl;
        float inv = 1.f / (reds[0][m] + reds[1][m] + reds[2][m] + reds[3][m]);
#pragma unroll
        for (int tr = 0; tr < 2; ++tr) {
            float uu = acc[tm][tr][reg] * inv;
            acc[tm][tr][reg] = uu;
            ub[(size_t)m * R + tr * 32 + col] = uu;
            cs[tr] += uu;
        }
    }
    unsigned short* uTb = uT + ((size_t)b * R + w * 64) * M + m0;
#pragma unroll
    for (int tm = 0; tm < 2; ++tm)
#pragma unroll
    for (int tr = 0; tr < 2; ++tr)
#pragma unroll
    for (int rq = 0; rq < 4; ++rq) {
        uint2 p;
        p.x = (unsigned)bf16_rtn(acc[tm][tr][rq*4+0]) | ((unsigned)bf16_rtn(acc[tm][tr][rq*4+1]) << 16);
        p.y = (unsigned)bf16_rtn(acc[tm][tr][rq*4+2]) | ((unsigned)bf16_rtn(acc[tm][tr][rq*4+3]) << 16);
        *(uint2*)(uTb + (size_t)(tr*32 + col) * M + tm*32 + 8*rq + 4*h5) = p;
    }
    cs[0] += __shfl_xor(cs[0], 32);
    cs[1] += __shfl_xor(cs[1], 32);
    if (h5 == 0) {
        atomicAdd(&colsum[b * R + w * 64 + col], cs[0]);
        atomicAdd(&colsum[b * R + w * 64 + 32 + col], cs[1]);
    }
}

// ---------------------------------------------------------------------------
// K2: partial v: part[slab][b][n][r] = sum_{m in slab} xT[n][m]*uT[r][m].
// grid (8 tiles, 8 slabs, B), block 256 (4 waves, 2x2 of 64x64 in 32x32 MFMA).
// Non-atomic coalesced fp32 stores.
// ---------------------------------------------------------------------------
__global__ __launch_bounds__(256, 4) void ekm_k2(
    const unsigned short* __restrict__ xT, const unsigned short* __restrict__ uT,
    float* __restrict__ part)
{
    __shared__ unsigned short XA[128 * 32], UB[128 * 32];
    const int t = threadIdx.x;
    const int nt = blockIdx.x >> 1, rt = blockIdx.x & 1;
    const int slab = blockIdx.y, b = blockIdx.z;
    const int n0 = nt * 128, r0 = rt * 128;
    const int w = t >> 6, l = t & 63, col = l & 31, h5 = l >> 5;
    const int wn = w >> 1, wr = w & 1;

    const unsigned short* xs = xT + ((size_t)b * N + n0 + (t >> 2)) * M + slab * 1024 + (t & 3) * 8;
    const unsigned short* us = uT + ((size_t)b * R + r0 + (t >> 2)) * M + slab * 1024 + (t & 3) * 8;

    f32x16 acc[2][2];
    acc[0][0] = (f32x16)0.f; acc[0][1] = (f32x16)0.f;
    acc[1][0] = (f32x16)0.f; acc[1][1] = (f32x16)0.f;

    for (int k0 = 0; k0 < 1024; k0 += 32) {
        __syncthreads();
#pragma unroll
        for (int i = 0; i < 2; ++i) {
            gll16(xs + k0 + (size_t)i * 64 * M, XA + i * 2048 + t * 8);
            gll16(us + k0 + (size_t)i * 64 * M, UB + i * 2048 + t * 8);
        }
        __syncthreads();
#pragma unroll
        for (int half = 0; half < 2; ++half) {
            short8 af[2], bf2[2];
#pragma unroll
            for (int tm = 0; tm < 2; ++tm)
                af[tm] = *(const short8*)&XA[(wn*64 + tm*32 + col) * 32 + half*16 + h5*8];
#pragma unroll
            for (int tr = 0; tr < 2; ++tr)
                bf2[tr] = *(const short8*)&UB[(wr*64 + tr*32 + col) * 32 + half*16 + h5*8];
#pragma unroll
            for (int tm = 0; tm < 2; ++tm)
#pragma unroll
            for (int tr = 0; tr < 2; ++tr)
                acc[tm][tr] = __builtin_amdgcn_mfma_f32_32x32x16_bf16(af[tm], bf2[tr], acc[tm][tr], 0, 0, 0);
        }
    }

    float* pb = part + (size_t)slab * ((size_t)B * N * R) + (size_t)b * N * R;
#pragma unroll
    for (int tm = 0; tm < 2; ++tm)
#pragma unroll
    for (int reg = 0; reg < 16; ++reg) {
        int n = n0 + wn*64 + tm*32 + (reg & 3) + 8*(reg >> 2) + 4*h5;
#pragma unroll
        for (int tr = 0; tr < 2; ++tr)
            pb[(size_t)n * R + r0 + wr*64 + tr*32 + col] = acc[tm][tr][reg];
    }
}

// ---------------------------------------------------------------------------
// Kred: v = (sum of 8 partial slabs) / (colsum + eps), float4 per thread.
// ---------------------------------------------------------------------------
__global__ __launch_bounds__(256) void ekm_red(
    const float* __restrict__ part, const float* __restrict__ colsum,
    float* __restrict__ v_out)
{
    size_t o = ((size_t)blockIdx.x * 256 + threadIdx.x) * 4;
    float sx = 0.f, sy = 0.f, sz = 0.f, sw = 0.f;
#pragma unroll
    for (int sl = 0; sl < 8; ++sl) {
        float4 p = *(const float4*)(part + (size_t)sl * B * N * R + o);
        sx += p.x; sy += p.y; sz += p.z; sw += p.w;
    }
    int b = (int)(o >> 17);           // N*R = 131072
    int r = (int)(o & (R - 1));
    float4 cs = *(const float4*)(colsum + b * R + r);
    float4 vo;
    vo.x = sx / (cs.x + EPSF);
    vo.y = sy / (cs.y + EPSF);
    vo.z = sz / (cs.z + EPSF);
    vo.w = sw / (cs.w + EPSF);
    *(float4*)(v_out + o) = vo;
}

extern "C" void kernel_launch(void* const* d_in, const int* in_sizes, int n_in,
                              void* d_out, int out_size, void* d_ws, size_t ws_size,
                              hipStream_t stream) {
    const float* x     = (const float*)d_in[0];
    const float* alpha = (const float*)d_in[1];
    const int*   inds  = (const int*)d_in[2];

    float* u_out = (float*)d_out;                    // B*M*R fp32
    float* v_out = u_out + (size_t)B * M * R;        // B*N*R fp32

    char* ws = (char*)d_ws;
    const size_t CH = (size_t)B * R * 512 * 2;       // 2 MB   c_hi / c_lo
    unsigned short* c_hi   = (unsigned short*)ws;
    unsigned short* c_lo   = (unsigned short*)(ws + CH);
    float*          v2g    = (float*)(ws + 2 * CH);
    float*          colsum = (float*)(ws + 2 * CH + (size_t)B * R * 4);
    char* p = ws + 2 * CH + 2 * (size_t)B * R * 4;
    unsigned short* xT = (unsigned short*)p;          p += (size_t)B * N * M * 2;  // 67 MB
    unsigned short* uT = (unsigned short*)p;          p += (size_t)B * R * M * 2;  // 33.5 MB
    float*          part = (float*)p;                 // 8 * B*N*R * 4 = 33.5 MB

    hipMemsetAsync(colsum, 0, (size_t)B * R * sizeof(float), stream);

    ekm_kc<<<dim3(16, B), 256, 0, stream>>>(x, inds, c_hi, c_lo, v2g);
    ekm_k1<<<dim3(M / 64, B), 256, 0, stream>>>(x, alpha, c_hi, c_lo, v2g,
                                                u_out, uT, xT, colsum);
    ekm_k2<<<dim3(8, 8, B), 256, 0, stream>>>(xT, uT, part);
    ekm_red<<<(B * N * R / 4) / 256, 256, 0, stream>>>(part, colsum, v_out);
}

// Round 4
// 347.458 us; speedup vs baseline: 1.9003x; 1.0331x over previous
//
#include <hip/hip_runtime.h>
#include <math.h>

#define B 8
#define M 8192
#define N 512
#define R 256
#define EPSF 1e-16f

typedef __attribute__((ext_vector_type(8))) short short8;
typedef __attribute__((ext_vector_type(16))) float f32x16;

__device__ __forceinline__ unsigned short bf16_rtn(float f) {
    unsigned int u = __float_as_uint(f);
    u += 0x7FFFu + ((u >> 16) & 1u);
    return (unsigned short)(u >> 16);
}

// async global->LDS, 16B per lane. LDS dest = wave-uniform base + lane*16.
__device__ __forceinline__ void gll16(const unsigned short* g, unsigned short* l) {
    __builtin_amdgcn_global_load_lds(
        (const __attribute__((address_space(1))) unsigned int*)g,
        (__attribute__((address_space(3))) unsigned int*)l, 16, 0, 0);
}

// ---------------------------------------------------------------------------
// Kc: gather centers x[b, inds, :] -> c_hi/c_lo (split bf16) + exact fp32 v2.
// ---------------------------------------------------------------------------
__global__ __launch_bounds__(256) void ekm_kc(
    const float* __restrict__ x, const int* __restrict__ inds,
    unsigned short* __restrict__ c_hi, unsigned short* __restrict__ c_lo,
    float* __restrict__ v2g)
{
    const int t = threadIdx.x, b = blockIdx.y;
    const int r = blockIdx.x * 16 + (t >> 4);
    const int seg = (t & 15) * 32;
    const float* src = x + ((size_t)b * M + inds[r]) * N + seg;
    unsigned short* hd = c_hi + ((size_t)b * R + r) * 512 + seg;
    unsigned short* ld = c_lo + ((size_t)b * R + r) * 512 + seg;
    float vp = 0.f;
#pragma unroll
    for (int c = 0; c < 4; ++c) {
        float4 f0 = *(const float4*)(src + c * 8);
        float4 f1 = *(const float4*)(src + c * 8 + 4);
        float av[8] = {f0.x, f0.y, f0.z, f0.w, f1.x, f1.y, f1.z, f1.w};
        unsigned ph[4], pl[4];
#pragma unroll
        for (int j = 0; j < 4; ++j) {
            vp += av[2*j] * av[2*j] + av[2*j+1] * av[2*j+1];
            unsigned short h0 = bf16_rtn(av[2*j]), h1 = bf16_rtn(av[2*j+1]);
            float r0 = av[2*j]   - __uint_as_float((unsigned)h0 << 16);
            float r1 = av[2*j+1] - __uint_as_float((unsigned)h1 << 16);
            ph[j] = (unsigned)h0 | ((unsigned)h1 << 16);
            pl[j] = (unsigned)bf16_rtn(r0) | ((unsigned)bf16_rtn(r1) << 16);
        }
        *(uint4*)(hd + c * 8) = make_uint4(ph[0], ph[1], ph[2], ph[3]);
        *(uint4*)(ld + c * 8) = make_uint4(pl[0], pl[1], pl[2], pl[3]);
    }
    vp += __shfl_xor(vp, 1); vp += __shfl_xor(vp, 2);
    vp += __shfl_xor(vp, 4); vp += __shfl_xor(vp, 8);
    if ((t & 15) == 0) v2g[b * R + r] = vp;
}

// ---------------------------------------------------------------------------
// K1: split-bf16 32x32x16 MFMA distances + fused softmax.
// XOR-swizzled B LDS (conflict-free), pipelined fp32 A prefetch.
// ---------------------------------------------------------------------------
__global__ __launch_bounds__(256, 3) void ekm_k1(
    const float* __restrict__ x, const float* __restrict__ alpha_p,
    const unsigned short* __restrict__ c_hi, const unsigned short* __restrict__ c_lo,
    const float* __restrict__ v2g, float* __restrict__ u_out,
    unsigned short* __restrict__ uT, unsigned short* __restrict__ xT,
    float* __restrict__ colsum)
{
    __shared__ unsigned short Ah[64 * 40], Al[64 * 40];   // padded (VGPR-staged)
    __shared__ unsigned short Bh[256 * 32], Bl[256 * 32]; // swizzled (gll)
    __shared__ float x2s[64];
    __shared__ float redm[4][64], reds[4][64];

    const int t = threadIdx.x;
    const int b = blockIdx.y;
    const int m0 = blockIdx.x * 64;
    const int w = t >> 6, l = t & 63, col = l & 31, h5 = l >> 5;
    const int arow = t >> 2, kch = t & 3;
    const int cswz = (t & 3) ^ ((t >> 3) & 3);   // swizzled source chunk for gll
    const int pswz = (col >> 1) & 3;             // fragment-read chunk XOR

    const float* ax = x + ((size_t)b * M + m0 + arow) * N + kch * 8;
    const unsigned short* bhs = c_hi + ((size_t)b * R + (t >> 2)) * 512 + cswz * 8;
    const unsigned short* bls = c_lo + ((size_t)b * R + (t >> 2)) * 512 + cswz * 8;

    f32x16 acc[2][2];
    acc[0][0] = (f32x16)0.f; acc[0][1] = (f32x16)0.f;
    acc[1][0] = (f32x16)0.f; acc[1][1] = (f32x16)0.f;

    float x2p = 0.f;
    float4 a0 = *(const float4*)(ax);
    float4 a1 = *(const float4*)(ax + 4);

    for (int k0 = 0; k0 < N; k0 += 32) {
        // convert prefetched A (fp32 -> hi/lo bf16), exact x2 accumulation
        x2p += a0.x*a0.x + a0.y*a0.y + a0.z*a0.z + a0.w*a0.w
             + a1.x*a1.x + a1.y*a1.y + a1.z*a1.z + a1.w*a1.w;
        float av[8] = {a0.x, a0.y, a0.z, a0.w, a1.x, a1.y, a1.z, a1.w};
        unsigned ph[4], pl[4];
#pragma unroll
        for (int j = 0; j < 4; ++j) {
            unsigned short h0 = bf16_rtn(av[2*j]), h1 = bf16_rtn(av[2*j+1]);
            float r0 = av[2*j]   - __uint_as_float((unsigned)h0 << 16);
            float r1 = av[2*j+1] - __uint_as_float((unsigned)h1 << 16);
            ph[j] = (unsigned)h0 | ((unsigned)h1 << 16);
            pl[j] = (unsigned)bf16_rtn(r0) | ((unsigned)bf16_rtn(r1) << 16);
        }
        __syncthreads();   // previous tile fully consumed
#pragma unroll
        for (int i = 0; i < 4; ++i) {
            gll16(bhs + k0 + i * (64 * 512), Bh + i * 2048 + t * 8);
            gll16(bls + k0 + i * (64 * 512), Bl + i * 2048 + t * 8);
        }
        *(uint4*)&Ah[arow * 40 + kch * 8] = make_uint4(ph[0], ph[1], ph[2], ph[3]);
        *(uint4*)&Al[arow * 40 + kch * 8] = make_uint4(pl[0], pl[1], pl[2], pl[3]);
        __syncthreads();   // drains gll (vmcnt) + LDS writes

        // prefetch next A AFTER the drain barrier -> hidden behind MFMA section
        if (k0 + 32 < N) {
            a0 = *(const float4*)(ax + k0 + 32);
            a1 = *(const float4*)(ax + k0 + 36);
        }

        // xT slab: [k0+kk][m0..m0+63], coalesced 16B stores
        {
            int kk = t >> 3, ms = (t & 7) * 8;
            unsigned q0 = (unsigned)Ah[(ms+0)*40+kk] | ((unsigned)Ah[(ms+1)*40+kk] << 16);
            unsigned q1 = (unsigned)Ah[(ms+2)*40+kk] | ((unsigned)Ah[(ms+3)*40+kk] << 16);
            unsigned q2 = (unsigned)Ah[(ms+4)*40+kk] | ((unsigned)Ah[(ms+5)*40+kk] << 16);
            unsigned q3 = (unsigned)Ah[(ms+6)*40+kk] | ((unsigned)Ah[(ms+7)*40+kk] << 16);
            *(uint4*)(xT + ((size_t)b * N + k0 + kk) * M + m0 + ms) = make_uint4(q0, q1, q2, q3);
        }

#pragma unroll
        for (int half = 0; half < 2; ++half) {
            const int pc = (half * 2 + h5) ^ pswz;   // physical chunk
            short8 ah[2], al2[2], bh[2], bl2[2];
#pragma unroll
            for (int tm = 0; tm < 2; ++tm) {
                ah[tm]  = *(const short8*)&Ah[(tm*32 + col) * 40 + half*16 + h5*8];
                al2[tm] = *(const short8*)&Al[(tm*32 + col) * 40 + half*16 + h5*8];
            }
#pragma unroll
            for (int tr = 0; tr < 2; ++tr) {
                bh[tr]  = *(const short8*)&Bh[(w*64 + tr*32 + col) * 32 + pc*8];
                bl2[tr] = *(const short8*)&Bl[(w*64 + tr*32 + col) * 32 + pc*8];
            }
#pragma unroll
            for (int tm = 0; tm < 2; ++tm)
#pragma unroll
            for (int tr = 0; tr < 2; ++tr) {
                acc[tm][tr] = __builtin_amdgcn_mfma_f32_32x32x16_bf16(ah[tm],  bh[tr],  acc[tm][tr], 0, 0, 0);
                acc[tm][tr] = __builtin_amdgcn_mfma_f32_32x32x16_bf16(ah[tm],  bl2[tr], acc[tm][tr], 0, 0, 0);
                acc[tm][tr] = __builtin_amdgcn_mfma_f32_32x32x16_bf16(al2[tm], bh[tr],  acc[tm][tr], 0, 0, 0);
            }
        }
    }

    // ---- epilogue ----
    x2p += __shfl_xor(x2p, 1);
    x2p += __shfl_xor(x2p, 2);
    if (kch == 0) x2s[arow] = x2p;
    __syncthreads();

    const float ia = 1.4426950408889634f / alpha_p[0];  // log2(e)/alpha
    float v2c[2];
#pragma unroll
    for (int tr = 0; tr < 2; ++tr)
        v2c[tr] = v2g[b * R + w * 64 + tr * 32 + col];

    // d = relu(x2 - 2xv + v2); wave-local row min; stage to LDS
#pragma unroll
    for (int tm = 0; tm < 2; ++tm)
#pragma unroll
    for (int reg = 0; reg < 16; ++reg) {
        int rowl = (reg & 3) + 8 * (reg >> 2) + 4 * h5;
        float x2v = x2s[tm * 32 + rowl];
        float mn;
#pragma unroll
        for (int tr = 0; tr < 2; ++tr) {
            float d = x2v - 2.f * acc[tm][tr][reg] + v2c[tr];
            d = fmaxf(d, 0.f);
            acc[tm][tr][reg] = d;
            mn = (tr == 0) ? d : fminf(mn, d);
        }
        mn = fminf(mn, __shfl_xor(mn, 1));
        mn = fminf(mn, __shfl_xor(mn, 2));
        mn = fminf(mn, __shfl_xor(mn, 4));
        mn = fminf(mn, __shfl_xor(mn, 8));
        mn = fminf(mn, __shfl_xor(mn, 16));
        if (col == 0) redm[w][tm * 32 + rowl] = mn;
    }
    __syncthreads();

    // exp + row sum
#pragma unroll
    for (int tm = 0; tm < 2; ++tm)
#pragma unroll
    for (int reg = 0; reg < 16; ++reg) {
        int m = tm * 32 + (reg & 3) + 8 * (reg >> 2) + 4 * h5;
        float mn = fminf(fminf(redm[0][m], redm[1][m]), fminf(redm[2][m], redm[3][m]));
        float s = 0.f;
#pragma unroll
        for (int tr = 0; tr < 2; ++tr) {
            float e = exp2f((mn - acc[tm][tr][reg]) * ia);
            acc[tm][tr][reg] = e;
            s += e;
        }
        s += __shfl_xor(s, 1); s += __shfl_xor(s, 2); s += __shfl_xor(s, 4);
        s += __shfl_xor(s, 8); s += __shfl_xor(s, 16);
        if (col == 0) reds[w][m] = s;
    }
    __syncthreads();

    // normalize, write u (fp32), accumulate colsum, pack uT (bf16)
    float* ub = u_out + ((size_t)b * M + m0) * R + w * 64;
    float cs[2] = {0.f, 0.f};
#pragma unroll
    for (int tm = 0; tm < 2; ++tm)
#pragma unroll
    for (int reg = 0; reg < 16; ++reg) {
        int rowl = (reg & 3) + 8 * (reg >> 2) + 4 * h5;
        int m = tm * 32 + rowl;
        float inv = 1.f / (reds[0][m] + reds[1][m] + reds[2][m] + reds[3][m]);
#pragma unroll
        for (int tr = 0; tr < 2; ++tr) {
            float uu = acc[tm][tr][reg] * inv;
            acc[tm][tr][reg] = uu;
            ub[(size_t)m * R + tr * 32 + col] = uu;
            cs[tr] += uu;
        }
    }
    unsigned short* uTb = uT + ((size_t)b * R + w * 64) * M + m0;
#pragma unroll
    for (int tm = 0; tm < 2; ++tm)
#pragma unroll
    for (int tr = 0; tr < 2; ++tr)
#pragma unroll
    for (int rq = 0; rq < 4; ++rq) {
        uint2 p;
        p.x = (unsigned)bf16_rtn(acc[tm][tr][rq*4+0]) | ((unsigned)bf16_rtn(acc[tm][tr][rq*4+1]) << 16);
        p.y = (unsigned)bf16_rtn(acc[tm][tr][rq*4+2]) | ((unsigned)bf16_rtn(acc[tm][tr][rq*4+3]) << 16);
        *(uint2*)(uTb + (size_t)(tr*32 + col) * M + tm*32 + 8*rq + 4*h5) = p;
    }
    cs[0] += __shfl_xor(cs[0], 32);
    cs[1] += __shfl_xor(cs[1], 32);
    if (h5 == 0) {
        atomicAdd(&colsum[b * R + w * 64 + col], cs[0]);
        atomicAdd(&colsum[b * R + w * 64 + 32 + col], cs[1]);
    }
}

// ---------------------------------------------------------------------------
// K2: part[slab][b][n][r] = sum_{m in slab} xT[n][m]*uT[r][m].
// Swizzled LDS, (256,2) bounds (no spills). Non-atomic coalesced stores.
// ---------------------------------------------------------------------------
__global__ __launch_bounds__(256, 2) void ekm_k2(
    const unsigned short* __restrict__ xT, const unsigned short* __restrict__ uT,
    float* __restrict__ part)
{
    __shared__ unsigned short XA[128 * 32], UB[128 * 32];
    const int t = threadIdx.x;
    const int nt = blockIdx.x >> 1, rt = blockIdx.x & 1;
    const int slab = blockIdx.y, b = blockIdx.z;
    const int n0 = nt * 128, r0 = rt * 128;
    const int w = t >> 6, l = t & 63, col = l & 31, h5 = l >> 5;
    const int wn = w >> 1, wr = w & 1;
    const int cswz = (t & 3) ^ ((t >> 3) & 3);
    const int pswz = (col >> 1) & 3;

    const unsigned short* xs = xT + ((size_t)b * N + n0 + (t >> 2)) * M + slab * 1024 + cswz * 8;
    const unsigned short* us = uT + ((size_t)b * R + r0 + (t >> 2)) * M + slab * 1024 + cswz * 8;

    f32x16 acc[2][2];
    acc[0][0] = (f32x16)0.f; acc[0][1] = (f32x16)0.f;
    acc[1][0] = (f32x16)0.f; acc[1][1] = (f32x16)0.f;

    for (int k0 = 0; k0 < 1024; k0 += 32) {
        __syncthreads();
#pragma unroll
        for (int i = 0; i < 2; ++i) {
            gll16(xs + k0 + (size_t)i * 64 * M, XA + i * 2048 + t * 8);
            gll16(us + k0 + (size_t)i * 64 * M, UB + i * 2048 + t * 8);
        }
        __syncthreads();
#pragma unroll
        for (int half = 0; half < 2; ++half) {
            const int pc = (half * 2 + h5) ^ pswz;
            short8 af[2], bf2[2];
#pragma unroll
            for (int tm = 0; tm < 2; ++tm)
                af[tm] = *(const short8*)&XA[(wn*64 + tm*32 + col) * 32 + pc*8];
#pragma unroll
            for (int tr = 0; tr < 2; ++tr)
                bf2[tr] = *(const short8*)&UB[(wr*64 + tr*32 + col) * 32 + pc*8];
#pragma unroll
            for (int tm = 0; tm < 2; ++tm)
#pragma unroll
            for (int tr = 0; tr < 2; ++tr)
                acc[tm][tr] = __builtin_amdgcn_mfma_f32_32x32x16_bf16(af[tm], bf2[tr], acc[tm][tr], 0, 0, 0);
        }
    }

    float* pb = part + (size_t)slab * ((size_t)B * N * R) + (size_t)b * N * R;
#pragma unroll
    for (int tm = 0; tm < 2; ++tm)
#pragma unroll
    for (int reg = 0; reg < 16; ++reg) {
        int n = n0 + wn*64 + tm*32 + (reg & 3) + 8*(reg >> 2) + 4*h5;
#pragma unroll
        for (int tr = 0; tr < 2; ++tr)
            pb[(size_t)n * R + r0 + wr*64 + tr*32 + col] = acc[tm][tr][reg];
    }
}

// ---------------------------------------------------------------------------
// Kred: v = (sum of 8 partial slabs) / (colsum + eps), float4 per thread.
// ---------------------------------------------------------------------------
__global__ __launch_bounds__(256) void ekm_red(
    const float* __restrict__ part, const float* __restrict__ colsum,
    float* __restrict__ v_out)
{
    size_t o = ((size_t)blockIdx.x * 256 + threadIdx.x) * 4;
    float sx = 0.f, sy = 0.f, sz = 0.f, sw = 0.f;
#pragma unroll
    for (int sl = 0; sl < 8; ++sl) {
        float4 p = *(const float4*)(part + (size_t)sl * B * N * R + o);
        sx += p.x; sy += p.y; sz += p.z; sw += p.w;
    }
    int b = (int)(o >> 17);           // N*R = 131072
    int r = (int)(o & (R - 1));
    float4 cs = *(const float4*)(colsum + b * R + r);
    float4 vo;
    vo.x = sx / (cs.x + EPSF);
    vo.y = sy / (cs.y + EPSF);
    vo.z = sz / (cs.z + EPSF);
    vo.w = sw / (cs.w + EPSF);
    *(float4*)(v_out + o) = vo;
}

extern "C" void kernel_launch(void* const* d_in, const int* in_sizes, int n_in,
                              void* d_out, int out_size, void* d_ws, size_t ws_size,
                              hipStream_t stream) {
    const float* x     = (const float*)d_in[0];
    const float* alpha = (const float*)d_in[1];
    const int*   inds  = (const int*)d_in[2];

    float* u_out = (float*)d_out;                    // B*M*R fp32
    float* v_out = u_out + (size_t)B * M * R;        // B*N*R fp32

    char* ws = (char*)d_ws;
    const size_t CH = (size_t)B * R * 512 * 2;       // 2 MB   c_hi / c_lo
    unsigned short* c_hi   = (unsigned short*)ws;
    unsigned short* c_lo   = (unsigned short*)(ws + CH);
    float*          v2g    = (float*)(ws + 2 * CH);
    float*          colsum = (float*)(ws + 2 * CH + (size_t)B * R * 4);
    char* p = ws + 2 * CH + 2 * (size_t)B * R * 4;
    unsigned short* xT = (unsigned short*)p;          p += (size_t)B * N * M * 2;  // 67 MB
    unsigned short* uT = (unsigned short*)p;          p += (size_t)B * R * M * 2;  // 33.5 MB
    float*          part = (float*)p;                 // 8 * B*N*R * 4 = 33.5 MB

    hipMemsetAsync(colsum, 0, (size_t)B * R * sizeof(float), stream);

    ekm_kc<<<dim3(16, B), 256, 0, stream>>>(x, inds, c_hi, c_lo, v2g);
    ekm_k1<<<dim3(M / 64, B), 256, 0, stream>>>(x, alpha, c_hi, c_lo, v2g,
                                                u_out, uT, xT, colsum);
    ekm_k2<<<dim3(8, 8, B), 256, 0, stream>>>(xT, uT, part);
    ekm_red<<<(B * N * R / 4) / 256, 256, 0, stream>>>(part, colsum, v_out);
}